// Round 14
// baseline (201.975 us; speedup 1.0000x reference)
//
#include <hip/hip_runtime.h>
#include <math.h>

#define EDIM 100
#define KP   128          // padded K
#define NF   4000
#define NN   4000
#define NB   8
#define NP   4096         // padded N and F
#define BN   128          // n-rows per block
#define BF   64           // f per tile
#define FPB  8            // tiles per block (8 x 64 f = 512 f)
#define NYB  8            // 4096 / 512

#define CONVB (3 * NP * 16 / 256)     // 768 convert blocks (short8 per thread)
#define PREPB 64                      // 64 P-blocks (one per 64-f group, all 8 b's)
#define E2B   ((NN + 255) / 256)      // 16 e2 blocks

typedef __attribute__((ext_vector_type(8))) short short8;
typedef __attribute__((ext_vector_type(4))) float floatx4;

typedef const __attribute__((address_space(1))) unsigned int* gas_u32;
typedef __attribute__((address_space(3))) unsigned int* las_u32;

// Static device scratch.
__device__ __align__(16) unsigned short g_A [NP * KP];   // ent  bf16, K-padded
__device__ __align__(16) unsigned short g_B1[NP * KP];   // fa1  bf16
__device__ __align__(16) unsigned short g_B2[NP * KP];   // fa2  bf16
// P in main-ready layout: [g][fgrp 64][chunk 128][ft 4] floats.
// chunk = c*8 + (b ^ (c&7))  -- XOR spreads the LDS fold-read across banks.
__device__ __align__(16) float g_P2[2 * 64 * 512];
__device__ float g_e2[NN];
__device__ float g_part[2 * NB * NYB * NP];              // [g][b][yblk][n]  (2 MB)
__device__ int g_cnt[2 * 32];                            // last-arriver counters [g][bx]

__device__ __forceinline__ unsigned short f2bf(float x) {
    union { float f; unsigned int u; } v; v.f = x;
    unsigned int r = v.u + 0x7FFFu + ((v.u >> 16) & 1u);  // RNE
    return (unsigned short)(r >> 16);
}

// 16-lane min reduction via DPP mirrors: XOR-masks {15,7,3,1} span all 16 lanes.
__device__ __forceinline__ float row16_min(float x) {
    int i;
    i = __builtin_amdgcn_mov_dpp(__float_as_int(x), 0x140, 0xF, 0xF, false); // row_mirror (^15)
    x = fminf(x, __int_as_float(i));
    i = __builtin_amdgcn_mov_dpp(__float_as_int(x), 0x141, 0xF, 0xF, false); // row_half_mirror (^7)
    x = fminf(x, __int_as_float(i));
    i = __builtin_amdgcn_mov_dpp(__float_as_int(x), 0x1B, 0xF, 0xF, false);  // quad reverse (^3)
    x = fminf(x, __int_as_float(i));
    i = __builtin_amdgcn_mov_dpp(__float_as_int(x), 0xB1, 0xF, 0xF, false);  // quad swap (^1)
    x = fminf(x, __int_as_float(i));
    return x;
}

// ---- merged prep: convert (768 blk) | P (64 blk, coalesced) | e2+cnt (16 blk) ----
__global__ void prep(const float* __restrict__ rel,  const float* __restrict__ arg1,
                     const float* __restrict__ arg2, const float* __restrict__ frel,
                     const float* __restrict__ fa1,  const float* __restrict__ fa2,
                     const float* __restrict__ ent) {
    __shared__ float sF[64 * 101];              // 25.9 KB, stride 101 (2-way bank max)
    const int bx = blockIdx.x;
    const int t  = threadIdx.x;

    if (bx < CONVB) {
        // fp32 [4000][100] -> bf16 [4096][128], one short8 (8 cols) per thread
        int plane = bx >> 8;                    // 256 blocks per plane
        int local = ((bx & 255) << 8) | t;      // 0 .. NP*16-1
        int row = local >> 4, j = local & 15;   // j = 8-col chunk
        const float* src = (plane == 0) ? ent : (plane == 1) ? fa1 : fa2;
        unsigned short* dst = (plane == 0) ? g_A : (plane == 1) ? g_B1 : g_B2;
        short8 o = (short8){0, 0, 0, 0, 0, 0, 0, 0};
        if (row < NF && j <= 12) {
            if (j < 12) {
                float4 v0 = *(const float4*)(src + row * EDIM + j * 8);
                float4 v1 = *(const float4*)(src + row * EDIM + j * 8 + 4);
                o[0] = (short)f2bf(v0.x); o[1] = (short)f2bf(v0.y);
                o[2] = (short)f2bf(v0.z); o[3] = (short)f2bf(v0.w);
                o[4] = (short)f2bf(v1.x); o[5] = (short)f2bf(v1.y);
                o[6] = (short)f2bf(v1.z); o[7] = (short)f2bf(v1.w);
            } else {  // j == 12: cols 96..99 valid, 100..103 zero
                float4 v0 = *(const float4*)(src + row * EDIM + 96);
                o[0] = (short)f2bf(v0.x); o[1] = (short)f2bf(v0.y);
                o[2] = (short)f2bf(v0.z); o[3] = (short)f2bf(v0.w);
            }
        }
        *(short8*)(dst + row * KP + j * 8) = o;
    } else if (bx < CONVB + PREPB) {
        // P for one 64-f group, ALL 8 b's.  3 passes (frel/fa1/fa2): stage 64x100
        // floats coalesced into LDS, then thread (fl = t&63, bq = t>>6) computes
        // dots for b = bq and bq+4 via LDS broadcast + wave-uniform s_loads.
        const int fbx = bx - CONVB;             // 0..63
        const int fl = t & 63;
        const int bq = t >> 6;                  // 0..3; owns b = bq, bq+4
        const int f  = fbx * 64 + fl;

        float nf = 0.f;
        float dr[2], d1[2], d2[2], qr[2], q1n[2], q2n[2];

        #pragma unroll 3
        for (int pass = 0; pass < 3; pass++) {
            const float* src = (pass == 0) ? frel : (pass == 1) ? fa1 : fa2;
            const float* qv  = (pass == 0) ? rel  : (pass == 1) ? arg1 : arg2;
            __syncthreads();                    // previous pass's reads done
            #pragma unroll
            for (int i = 0; i < 25; i++) {      // 6400 floats, coalesced
                int idx = i * 256 + t;
                int row = idx / 100, col = idx - row * 100;
                int fr = fbx * 64 + row; if (fr > NF - 1) fr = NF - 1;
                sF[row * 101 + col] = src[fr * EDIM + col];
            }
            __syncthreads();
            float dot0 = 0.f, dot1 = 0.f, qn0 = 0.f, qn1 = 0.f, fn = 0.f;
            #pragma unroll 4
            for (int k = 0; k < EDIM; k++) {
                float fv = sF[fl * 101 + k];
                float u0 = qv[bq * EDIM + k];          // wave-uniform -> s_load
                float u1 = qv[(bq + 4) * EDIM + k];
                dot0 = fmaf(fv, u0, dot0);
                dot1 = fmaf(fv, u1, dot1);
                qn0  = fmaf(u0, u0, qn0);
                qn1  = fmaf(u1, u1, qn1);
                fn   = fmaf(fv, fv, fn);
            }
            nf += fn;
            if (pass == 0) { dr[0] = dot0; dr[1] = dot1; qr[0] = qn0; qr[1] = qn1; }
            else if (pass == 1) { d1[0] = dot0; d1[1] = dot1; q1n[0] = qn0; q1n[1] = qn1; }
            else { d2[0] = dot0; d2[1] = dot1; q2n[0] = qn0; q2n[1] = qn1; }
        }

        const int cc = fl & 15;                 // f & 15
        const int ft = fl >> 4;                 // (f & 63) >> 4
        #pragma unroll
        for (int bi = 0; bi < 2; bi++) {
            int b = bq + bi * 4;
            float psp = nf + qr[bi] + q1n[bi] - 2.f * (dr[bi] + d1[bi]);
            float ppo = nf + qr[bi] + q2n[bi] - 2.f * (dr[bi] + d2[bi]);
            if (f >= NF) { psp = __builtin_inff(); ppo = __builtin_inff(); }
            int chunk = cc * 8 + (b ^ (cc & 7));
            g_P2[(0 * 64 + fbx) * 512 + chunk * 4 + ft] = psp;
            g_P2[(1 * 64 + fbx) * 512 + chunk * 4 + ft] = ppo;
        }
    } else {
        int bb = bx - CONVB - PREPB;
        if (bb == 0 && t < 64) g_cnt[t] = 0;    // reset last-arriver counters (graph replay)
        int n = bb * 256 + t;
        if (n < NN) {
            const float4* ep = (const float4*)(ent + n * EDIM);
            float s = 0.f;
            #pragma unroll
            for (int i = 0; i < EDIM / 4; i++) {
                float4 v = ep[i];
                s += v.x * v.x + v.y * v.y + v.z * v.z + v.w * v.w;
            }
            g_e2[n] = s;
        }
    }
}

// Main: grid (32, 8, 2), 512 threads (8 waves); z = g.  r9's EXACT loop body,
// register set, and 2-buffer __syncthreads pipeline (measured best; r10-r12
// variants all null or spilled).  NEW: finalize merged as a last-arriver
// epilogue -- the 8 blocks sharing (g, bx) count down on g_cnt; the 8th reads
// all NYB partial columns and writes the final exp outputs.  No spin-waits
// (deadlock-impossible regardless of dispatch order); device-scope fences
// per XCD-coherence rules (G16).
// launch_bounds(512,4): VGPR cap 128.  Spill tripwire: WRITE >> 2.5 MB.
__global__ void __launch_bounds__(512, 4) main_kernel(float* __restrict__ out) {
    __shared__ __align__(16) unsigned short sB[2][BF * 128]; // 2 x 16 KB, chunk-swizzled
    __shared__ __align__(16) float sP[2][512];               // 2 x 2 KB
    __shared__ int lastFlag;

    const int t = threadIdx.x;
    const int n0 = blockIdx.x * BN;
    const int by = blockIdx.y;
    const int g  = blockIdx.z;
    const int lane = t & 63;
    const int c = lane & 15;
    const int q = lane >> 4;
    const int w = t >> 6;                        // 0..7
    const int w16 = w * 16;

    const unsigned short* gB = g ? g_B1 : g_B2;  // g=0(sp): entity . fa2; g=1(po): . fa1

    // ---- A fragments direct from global, hoisted across all tiles ----
    short8 afrag[4];                             // [s]  (16 VGPR)
    #pragma unroll
    for (int s = 0; s < 4; s++)
        afrag[s] = *(const short8*)(g_A + (n0 + w16 + c) * KP + (s * 4 + q) * 8);

    floatx4 m2[NB];                              // [b] running min (32 VGPR)
    #pragma unroll
    for (int b = 0; b < NB; b++)
        m2[b] = (floatx4){__builtin_inff(), __builtin_inff(),
                          __builtin_inff(), __builtin_inff()};

    // DMA-stage one 64-f tile (16 KB B + 2 KB P) into buffer buf.
    // LDS dest is linear (wave base + lane*16); swizzle folded into global source.
    auto stage = [&](int buf, int fb) {
        const int f0r = fb * BF;
        #pragma unroll
        for (int j = 0; j < 2; j++) {
            int ck = (w * 2 + j) * 64 + lane;                 // dest chunk index
            int rw = ck >> 4, ch = ck & 15;
            int src = (f0r + rw) * 16 + (ch ^ (rw & 15));     // source chunk (pre-swizzle)
            __builtin_amdgcn_global_load_lds(
                (gas_u32)(gB + src * 8),
                (las_u32)(&sB[buf][(w * 2 + j) * 512]),
                16, 0, 0);
        }
        if (w < 2)
            __builtin_amdgcn_global_load_lds(
                (gas_u32)(g_P2 + (g * 64 + fb) * 512 + w * 256 + lane * 4),
                (las_u32)(&sP[buf][w * 256]),
                16, 0, 0);
    };

    stage(0, by * FPB);
    __syncthreads();   // vmcnt(0) drain: buffer 0 ready

    #pragma unroll 1
    for (int ib = 0; ib < FPB; ib++) {
        const int cur = ib & 1;
        if (ib + 1 < FPB) stage(cur ^ 1, by * FPB + ib + 1);  // async, drains at barrier

        const short8* pB = (const short8*)sB[cur];
        floatx4 acc[4];                          // [ft]
        #pragma unroll
        for (int ft = 0; ft < 4; ft++)
            acc[ft] = (floatx4){0.f, 0.f, 0.f, 0.f};

        #pragma unroll
        for (int s = 0; s < 4; s++) {            // K-steps of 32
            const int base = s * 4 + q;
            #pragma unroll
            for (int ft = 0; ft < 4; ft++) {
                short8 bb = pB[(ft * 16 + c) * 16 + (base ^ c)];
                acc[ft] = __builtin_amdgcn_mfma_f32_16x16x32_bf16(afrag[s], bb, acc[ft], 0, 0, 0);
            }
        }

        // ---- fold P in acc layout: f = ft*16 + c; one b128 per b ----
        const float* Pf = sP[cur];
        #pragma unroll
        for (int b = 0; b < NB; b++) {
            floatx4 p = *(const floatx4*)(Pf + (c * 8 + (b ^ (c & 7))) * 4);
            #pragma unroll
            for (int r = 0; r < 4; r++) {
                float t0 = fmaf(-2.f, acc[0][r], p[0]);
                float t1 = fmaf(-2.f, acc[1][r], p[1]);
                float t2 = fmaf(-2.f, acc[2][r], p[2]);
                float t3 = fmaf(-2.f, acc[3][r], p[3]);
                float u = fminf(fminf(t0, t1), t2);               // v_min3
                m2[b][r] = fminf(fminf(u, t3), m2[b][r]);         // v_min3
            }
        }
        if (ib + 1 < FPB) __syncthreads();       // next buffer staged + this one reusable
    }

    // ---- once: reduce over 16 c-lanes (DPP, pure VALU) ----
    #pragma unroll
    for (int b = 0; b < NB; b++)
        #pragma unroll
        for (int r = 0; r < 4; r++)
            m2[b][r] = row16_min(m2[b][r]);

    if (c == 0) {
        #pragma unroll
        for (int b = 0; b < NB; b++)
            *(float4*)&g_part[((g * NB + b) * NYB + by) * NP + n0 + w16 + q * 4] =
                (float4){m2[b][0], m2[b][1], m2[b][2], m2[b][3]};
    }

    // ---- merged finalize: last block per (g, bx) column does it ----
    __threadfence();                             // release: all threads' g_part writes
    __syncthreads();
    if (t == 0)
        lastFlag = (atomicAdd(&g_cnt[g * 32 + blockIdx.x], 1) == NYB - 1);
    __syncthreads();
    if (!lastFlag) return;
    __threadfence();                             // acquire: invalidate stale caches

    // 1024 outputs for this (g, n0..n0+127) column: local = b*128 + nl.
    #pragma unroll
    for (int u = 0; u < 2; u++) {
        int local = u * 512 + t;
        int b  = local >> 7;
        int nl = local & 127;
        int n  = n0 + nl;
        if (n < NN) {
            int sb = g * NB + b;
            float m = __builtin_inff();
            #pragma unroll
            for (int j = 0; j < NYB; j += 2) {   // identical pairing to old finalize
                float a  = g_part[(sb * NYB + j) * NP + n];
                float bv = g_part[(sb * NYB + j + 1) * NP + n];
                m = fminf(m, fminf(a, bv));      // v_min3
            }
            float d2 = fmaxf(m + g_e2[n], 0.f);
            out[sb * NN + n] = expf(-0.5f * d2);
        }
    }
}

extern "C" void kernel_launch(void* const* d_in, const int* in_sizes, int n_in,
                              void* d_out, int out_size, void* d_ws, size_t ws_size,
                              hipStream_t stream) {
    const float* rel  = (const float*)d_in[0];
    const float* arg1 = (const float*)d_in[1];
    const float* arg2 = (const float*)d_in[2];
    const float* frel = (const float*)d_in[3];
    const float* fa1  = (const float*)d_in[4];
    const float* fa2  = (const float*)d_in[5];
    const float* ent  = (const float*)d_in[6];
    float* out = (float*)d_out;

    prep<<<dim3(CONVB + PREPB + E2B), 256, 0, stream>>>(rel, arg1, arg2, frel, fa1, fa2, ent);
    main_kernel<<<dim3(NP / BN, NYB, 2), 512, 0, stream>>>(out);
}

// Round 15
// 109.729 us; speedup vs baseline: 1.8407x; 1.8407x over previous
//
#include <hip/hip_runtime.h>
#include <math.h>

#define EDIM 100
#define KP   128          // padded K
#define NF   4000
#define NN   4000
#define NB   8
#define NP   4096         // padded N and F
#define BN   128          // n-rows per block
#define BF   64           // f per tile
#define FPB  8            // tiles per block (8 x 64 f = 512 f)
#define NYB  8            // 4096 / 512

#define CONVB (3 * NP * 16 / 256)     // 768 convert blocks (short8 per thread)
#define PREPB 64                      // 64 P-blocks (one per 64-f group, all 8 b's)
#define E2B   ((NN + 255) / 256)      // 16 e2 blocks

typedef __attribute__((ext_vector_type(8))) short short8;
typedef __attribute__((ext_vector_type(4))) float floatx4;

typedef const __attribute__((address_space(1))) unsigned int* gas_u32;
typedef __attribute__((address_space(3))) unsigned int* las_u32;

// Static device scratch.
__device__ __align__(16) unsigned short g_A [NP * KP];   // ent  bf16, K-padded
__device__ __align__(16) unsigned short g_B1[NP * KP];   // fa1  bf16
__device__ __align__(16) unsigned short g_B2[NP * KP];   // fa2  bf16
// P in main-ready layout: [g][fgrp 64][chunk 128][ft 4] floats.
// chunk = c*8 + (b ^ (c&7))  -- XOR spreads the LDS fold-read across banks.
__device__ __align__(16) float g_P2[2 * 64 * 512];
__device__ float g_e2[NN];
__device__ float g_part[2 * NB * NYB * NP];              // [g][b][yblk][n]  (2 MB)

__device__ __forceinline__ unsigned short f2bf(float x) {
    union { float f; unsigned int u; } v; v.f = x;
    unsigned int r = v.u + 0x7FFFu + ((v.u >> 16) & 1u);  // RNE
    return (unsigned short)(r >> 16);
}

// 16-lane min reduction via DPP mirrors: XOR-masks {15,7,3,1} span all 16 lanes.
__device__ __forceinline__ float row16_min(float x) {
    int i;
    i = __builtin_amdgcn_mov_dpp(__float_as_int(x), 0x140, 0xF, 0xF, false); // row_mirror (^15)
    x = fminf(x, __int_as_float(i));
    i = __builtin_amdgcn_mov_dpp(__float_as_int(x), 0x141, 0xF, 0xF, false); // row_half_mirror (^7)
    x = fminf(x, __int_as_float(i));
    i = __builtin_amdgcn_mov_dpp(__float_as_int(x), 0x1B, 0xF, 0xF, false);  // quad reverse (^3)
    x = fminf(x, __int_as_float(i));
    i = __builtin_amdgcn_mov_dpp(__float_as_int(x), 0xB1, 0xF, 0xF, false);  // quad swap (^1)
    x = fminf(x, __int_as_float(i));
    return x;
}

// ---- merged prep: convert (768 blk) | P (64 blk, coalesced) | e2 (16 blk) ----
__global__ void prep(const float* __restrict__ rel,  const float* __restrict__ arg1,
                     const float* __restrict__ arg2, const float* __restrict__ frel,
                     const float* __restrict__ fa1,  const float* __restrict__ fa2,
                     const float* __restrict__ ent) {
    __shared__ float sF[64 * 101];              // 25.9 KB, stride 101 (2-way bank max)
    const int bx = blockIdx.x;
    const int t  = threadIdx.x;

    if (bx < CONVB) {
        // fp32 [4000][100] -> bf16 [4096][128], one short8 (8 cols) per thread
        int plane = bx >> 8;                    // 256 blocks per plane
        int local = ((bx & 255) << 8) | t;      // 0 .. NP*16-1
        int row = local >> 4, j = local & 15;   // j = 8-col chunk
        const float* src = (plane == 0) ? ent : (plane == 1) ? fa1 : fa2;
        unsigned short* dst = (plane == 0) ? g_A : (plane == 1) ? g_B1 : g_B2;
        short8 o = (short8){0, 0, 0, 0, 0, 0, 0, 0};
        if (row < NF && j <= 12) {
            if (j < 12) {
                float4 v0 = *(const float4*)(src + row * EDIM + j * 8);
                float4 v1 = *(const float4*)(src + row * EDIM + j * 8 + 4);
                o[0] = (short)f2bf(v0.x); o[1] = (short)f2bf(v0.y);
                o[2] = (short)f2bf(v0.z); o[3] = (short)f2bf(v0.w);
                o[4] = (short)f2bf(v1.x); o[5] = (short)f2bf(v1.y);
                o[6] = (short)f2bf(v1.z); o[7] = (short)f2bf(v1.w);
            } else {  // j == 12: cols 96..99 valid, 100..103 zero
                float4 v0 = *(const float4*)(src + row * EDIM + 96);
                o[0] = (short)f2bf(v0.x); o[1] = (short)f2bf(v0.y);
                o[2] = (short)f2bf(v0.z); o[3] = (short)f2bf(v0.w);
            }
        }
        *(short8*)(dst + row * KP + j * 8) = o;
    } else if (bx < CONVB + PREPB) {
        // P for one 64-f group, ALL 8 b's.  3 passes (frel/fa1/fa2): stage 64x100
        // floats coalesced into LDS, then thread (fl = t&63, bq = t>>6) computes
        // dots for b = bq and bq+4 via LDS broadcast + wave-uniform s_loads.
        const int fbx = bx - CONVB;             // 0..63
        const int fl = t & 63;
        const int bq = t >> 6;                  // 0..3; owns b = bq, bq+4
        const int f  = fbx * 64 + fl;

        float nf = 0.f;
        float dr[2], d1[2], d2[2], qr[2], q1n[2], q2n[2];

        #pragma unroll 3
        for (int pass = 0; pass < 3; pass++) {
            const float* src = (pass == 0) ? frel : (pass == 1) ? fa1 : fa2;
            const float* qv  = (pass == 0) ? rel  : (pass == 1) ? arg1 : arg2;
            __syncthreads();                    // previous pass's reads done
            #pragma unroll
            for (int i = 0; i < 25; i++) {      // 6400 floats, coalesced
                int idx = i * 256 + t;
                int row = idx / 100, col = idx - row * 100;
                int fr = fbx * 64 + row; if (fr > NF - 1) fr = NF - 1;
                sF[row * 101 + col] = src[fr * EDIM + col];
            }
            __syncthreads();
            float dot0 = 0.f, dot1 = 0.f, qn0 = 0.f, qn1 = 0.f, fn = 0.f;
            #pragma unroll 4
            for (int k = 0; k < EDIM; k++) {
                float fv = sF[fl * 101 + k];
                float u0 = qv[bq * EDIM + k];          // wave-uniform -> s_load
                float u1 = qv[(bq + 4) * EDIM + k];
                dot0 = fmaf(fv, u0, dot0);
                dot1 = fmaf(fv, u1, dot1);
                qn0  = fmaf(u0, u0, qn0);
                qn1  = fmaf(u1, u1, qn1);
                fn   = fmaf(fv, fv, fn);
            }
            nf += fn;
            if (pass == 0) { dr[0] = dot0; dr[1] = dot1; qr[0] = qn0; qr[1] = qn1; }
            else if (pass == 1) { d1[0] = dot0; d1[1] = dot1; q1n[0] = qn0; q1n[1] = qn1; }
            else { d2[0] = dot0; d2[1] = dot1; q2n[0] = qn0; q2n[1] = qn1; }
        }

        const int cc = fl & 15;                 // f & 15
        const int ft = fl >> 4;                 // (f & 63) >> 4
        #pragma unroll
        for (int bi = 0; bi < 2; bi++) {
            int b = bq + bi * 4;
            float psp = nf + qr[bi] + q1n[bi] - 2.f * (dr[bi] + d1[bi]);
            float ppo = nf + qr[bi] + q2n[bi] - 2.f * (dr[bi] + d2[bi]);
            if (f >= NF) { psp = __builtin_inff(); ppo = __builtin_inff(); }
            int chunk = cc * 8 + (b ^ (cc & 7));
            g_P2[(0 * 64 + fbx) * 512 + chunk * 4 + ft] = psp;
            g_P2[(1 * 64 + fbx) * 512 + chunk * 4 + ft] = ppo;
        }
    } else {
        int n = (bx - CONVB - PREPB) * 256 + t;
        if (n < NN) {
            const float4* ep = (const float4*)(ent + n * EDIM);
            float s = 0.f;
            #pragma unroll
            for (int i = 0; i < EDIM / 4; i++) {
                float4 v = ep[i];
                s += v.x * v.x + v.y * v.y + v.z * v.z + v.w * v.w;
            }
            g_e2[n] = s;
        }
    }
}

// Main: grid (32, 8, 2), 512 threads (8 waves); z = g.  Session-best form (r9,
// 110.2 us total): per block 128 n-rows x 8 tiles of 64 f; 512 blocks =
// 2 blocks/CU, one resident round, 4 waves/SIMD.  A fragments hoisted in
// registers (direct global); B + P double-buffered in LDS via global_load_lds
// (pre-swizzled source); P folded directly in MFMA accumulator layout;
// running min in 32 VGPRs; DPP c-reduce once at the end.
// DO NOT restructure this body: r6/r10/r11/r14 all collapsed the register
// allocator (VGPR 64-84 + scratch serialization) on any body change --
// including a post-loop atomic epilogue (r14).  VGPR_Count ~100 is the
// health signal; WRITE_SIZE may hide L2-resident spill.
__global__ void __launch_bounds__(512, 4) main_kernel() {
    __shared__ __align__(16) unsigned short sB[2][BF * 128]; // 2 x 16 KB, chunk-swizzled
    __shared__ __align__(16) float sP[2][512];               // 2 x 2 KB

    const int t = threadIdx.x;
    const int n0 = blockIdx.x * BN;
    const int by = blockIdx.y;
    const int g  = blockIdx.z;
    const int lane = t & 63;
    const int c = lane & 15;
    const int q = lane >> 4;
    const int w = t >> 6;                        // 0..7
    const int w16 = w * 16;

    const unsigned short* gB = g ? g_B1 : g_B2;  // g=0(sp): entity . fa2; g=1(po): . fa1

    // ---- A fragments direct from global, hoisted across all tiles ----
    short8 afrag[4];                             // [s]  (16 VGPR)
    #pragma unroll
    for (int s = 0; s < 4; s++)
        afrag[s] = *(const short8*)(g_A + (n0 + w16 + c) * KP + (s * 4 + q) * 8);

    floatx4 m2[NB];                              // [b] running min (32 VGPR)
    #pragma unroll
    for (int b = 0; b < NB; b++)
        m2[b] = (floatx4){__builtin_inff(), __builtin_inff(),
                          __builtin_inff(), __builtin_inff()};

    // DMA-stage one 64-f tile (16 KB B + 2 KB P) into buffer buf.
    // LDS dest is linear (wave base + lane*16); swizzle folded into global source.
    auto stage = [&](int buf, int fb) {
        const int f0r = fb * BF;
        #pragma unroll
        for (int j = 0; j < 2; j++) {
            int ck = (w * 2 + j) * 64 + lane;                 // dest chunk index
            int rw = ck >> 4, ch = ck & 15;
            int src = (f0r + rw) * 16 + (ch ^ (rw & 15));     // source chunk (pre-swizzle)
            __builtin_amdgcn_global_load_lds(
                (gas_u32)(gB + src * 8),
                (las_u32)(&sB[buf][(w * 2 + j) * 512]),
                16, 0, 0);
        }
        if (w < 2)
            __builtin_amdgcn_global_load_lds(
                (gas_u32)(g_P2 + (g * 64 + fb) * 512 + w * 256 + lane * 4),
                (las_u32)(&sP[buf][w * 256]),
                16, 0, 0);
    };

    stage(0, by * FPB);
    __syncthreads();   // vmcnt(0) drain: buffer 0 ready

    #pragma unroll 1
    for (int ib = 0; ib < FPB; ib++) {
        const int cur = ib & 1;
        if (ib + 1 < FPB) stage(cur ^ 1, by * FPB + ib + 1);  // async, drains at barrier

        const short8* pB = (const short8*)sB[cur];
        floatx4 acc[4];                          // [ft]
        #pragma unroll
        for (int ft = 0; ft < 4; ft++)
            acc[ft] = (floatx4){0.f, 0.f, 0.f, 0.f};

        #pragma unroll
        for (int s = 0; s < 4; s++) {            // K-steps of 32
            const int base = s * 4 + q;
            #pragma unroll
            for (int ft = 0; ft < 4; ft++) {
                short8 bb = pB[(ft * 16 + c) * 16 + (base ^ c)];
                acc[ft] = __builtin_amdgcn_mfma_f32_16x16x32_bf16(afrag[s], bb, acc[ft], 0, 0, 0);
            }
        }

        // ---- fold P in acc layout: f = ft*16 + c; one b128 per b ----
        const float* Pf = sP[cur];
        #pragma unroll
        for (int b = 0; b < NB; b++) {
            floatx4 p = *(const floatx4*)(Pf + (c * 8 + (b ^ (c & 7))) * 4);
            #pragma unroll
            for (int r = 0; r < 4; r++) {
                float t0 = fmaf(-2.f, acc[0][r], p[0]);
                float t1 = fmaf(-2.f, acc[1][r], p[1]);
                float t2 = fmaf(-2.f, acc[2][r], p[2]);
                float t3 = fmaf(-2.f, acc[3][r], p[3]);
                float u = fminf(fminf(t0, t1), t2);               // v_min3
                m2[b][r] = fminf(fminf(u, t3), m2[b][r]);         // v_min3
            }
        }
        if (ib + 1 < FPB) __syncthreads();       // next buffer staged + this one reusable
    }

    // ---- once: reduce over 16 c-lanes (DPP, pure VALU) ----
    #pragma unroll
    for (int b = 0; b < NB; b++)
        #pragma unroll
        for (int r = 0; r < 4; r++)
            m2[b][r] = row16_min(m2[b][r]);

    if (c == 0) {
        #pragma unroll
        for (int b = 0; b < NB; b++)
            *(float4*)&g_part[((g * NB + b) * NYB + by) * NP + n0 + w16 + q * 4] =
                (float4){m2[b][0], m2[b][1], m2[b][2], m2[b][3]};
    }
}

__global__ void finalize(float* __restrict__ out) {
    int idx = blockIdx.x * 256 + threadIdx.x;   // over 2*NB*NN, out layout (g*NB+b)*NN+n
    if (idx >= 2 * NB * NN) return;
    int sb = idx / NN;
    int n = idx % NN;
    float m = __builtin_inff();
    #pragma unroll
    for (int j = 0; j < NYB; j += 2) {
        float a = g_part[(sb * NYB + j) * NP + n];
        float b = g_part[(sb * NYB + j + 1) * NP + n];
        m = fminf(m, fminf(a, b));              // v_min3
    }
    float d2 = fmaxf(m + g_e2[n], 0.f);
    out[idx] = expf(-0.5f * d2);
}

extern "C" void kernel_launch(void* const* d_in, const int* in_sizes, int n_in,
                              void* d_out, int out_size, void* d_ws, size_t ws_size,
                              hipStream_t stream) {
    const float* rel  = (const float*)d_in[0];
    const float* arg1 = (const float*)d_in[1];
    const float* arg2 = (const float*)d_in[2];
    const float* frel = (const float*)d_in[3];
    const float* fa1  = (const float*)d_in[4];
    const float* fa2  = (const float*)d_in[5];
    const float* ent  = (const float*)d_in[6];
    float* out = (float*)d_out;

    prep<<<dim3(CONVB + PREPB + E2B), 256, 0, stream>>>(rel, arg1, arg2, frel, fa1, fa2, ent);
    main_kernel<<<dim3(NP / BN, NYB, 2), 512, 0, stream>>>();
    finalize<<<(2 * NB * NN + 255) / 256, 256, 0, stream>>>(out);
}